// Round 5
// baseline (2547.702 us; speedup 1.0000x reference)
//
#include <hip/hip_runtime.h>

typedef unsigned short ushort_t;
typedef float  f32x4   __attribute__((ext_vector_type(4)));
typedef float  f32x16  __attribute__((ext_vector_type(16)));
typedef __bf16 bf16x8  __attribute__((ext_vector_type(8)));

#define MFMA16(a,b,c) __builtin_amdgcn_mfma_f32_16x16x32_bf16((a),(b),(c),0,0,0)
#define MFMA32(a,b,c) __builtin_amdgcn_mfma_f32_32x32x16_bf16((a),(b),(c),0,0,0)

__device__ __forceinline__ ushort_t f2bf(float f) {
  union { float f; unsigned u; } v; v.f = f;
  unsigned u = v.u;
  unsigned r = u + 0x7FFFu + ((u >> 16) & 1u);   // round-to-nearest-even
  return (ushort_t)(r >> 16);
}
__device__ __forceinline__ float bf2f(ushort_t s) {
  union { unsigned u; float f; } v; v.u = ((unsigned)s) << 16;
  return v.f;
}

// ---------------------------------------------------------------------------
// Kernel 1: fused grouped conv (MFMA) + bias; x staged once per block (f32 ->
// bf16 transpose in LDS), loops 3 branches x 4 ngsub. Writes unnormalized y
// in final layouts; accumulates GroupNorm partial sums via atomics.
// grid (pc=16, g*b=64), 256 thr.
// Q branch -> [B][C][P]; K/V branches -> [B][H][P][128].
// ---------------------------------------------------------------------------
__global__ __launch_bounds__(256) void conv_gn(
    const float* __restrict__ x,
    const float* __restrict__ wq, const float* __restrict__ wk, const float* __restrict__ wv,
    const float* __restrict__ bq, const float* __restrict__ bk, const float* __restrict__ bv,
    ushort_t* __restrict__ Qb, ushort_t* __restrict__ Kb, ushort_t* __restrict__ Vb,
    float* __restrict__ stats) {
  int pc = blockIdx.x;
  int gz = blockIdx.y;
  int b = gz & 7, g = gz >> 3;
  int tid = threadIdx.x, lane = tid & 63, wid = tid >> 6;
  int l15 = lane & 15, q = lane >> 4;

  __shared__ __align__(16) ushort_t xl[128 * 72];   // [p][f]
  __shared__ __align__(16) ushort_t wl[128 * 72];   // [co][f], one branch
  __shared__ __align__(16) ushort_t yl[128 * 40];   // staging (br=0 uses [32][136])
  __shared__ float biasl[128];
  __shared__ float redbuf[8];

  // stage x tile [64 f][128 p] f32 -> xl[p][f] bf16
  const float* xsrc = x + ((size_t)(b * 512 + g * 64)) * 2048 + pc * 128;
#pragma unroll
  for (int r = 0; r < 8; ++r) {
    int chunk = tid + 256 * r;
    int c = chunk >> 5, p4 = chunk & 31;
    float4 v = *(const float4*)&xsrc[(size_t)c * 2048 + p4 * 4];
    xl[(p4 * 4 + 0) * 72 + c] = f2bf(v.x);
    xl[(p4 * 4 + 1) * 72 + c] = f2bf(v.y);
    xl[(p4 * 4 + 2) * 72 + c] = f2bf(v.z);
    xl[(p4 * 4 + 3) * 72 + c] = f2bf(v.w);
  }
  __syncthreads();

  // resident B-frags (wave's 32 p-cols)
  bf16x8 Bx[2][2];
#pragma unroll
  for (int n2 = 0; n2 < 2; ++n2)
#pragma unroll
    for (int kk = 0; kk < 2; ++kk)
      Bx[n2][kk] = *(const bf16x8*)&xl[((wid * 2 + n2) * 16 + l15) * 72 + kk * 32 + q * 8];

  for (int br = 0; br < 3; ++br) {
    const float* w    = (br == 0) ? wq : ((br == 1) ? wk : wv);
    const float* bias = (br == 0) ? bq : ((br == 1) ? bk : bv);
    ushort_t* dst     = (br == 0) ? Qb : ((br == 1) ? Kb : Vb);
    __syncthreads();   // previous branch's wl/yl consumers done
    const float* wsrc = w + (size_t)g * 128 * 64;
#pragma unroll
    for (int r = 0; r < 8; ++r) {
      int idx = (tid + 256 * r) << 2;
      float4 v = *(const float4*)&wsrc[idx];
      int row = idx >> 6, f = idx & 63;
      wl[row * 72 + f + 0] = f2bf(v.x);
      wl[row * 72 + f + 1] = f2bf(v.y);
      wl[row * 72 + f + 2] = f2bf(v.z);
      wl[row * 72 + f + 3] = f2bf(v.w);
    }
    if (tid < 128) biasl[tid] = bias[g * 128 + tid];
    __syncthreads();

    for (int ngs = 0; ngs < 4; ++ngs) {
      int co0 = ngs * 32;
      bf16x8 Aw[2][2];
#pragma unroll
      for (int m = 0; m < 2; ++m)
#pragma unroll
        for (int kk = 0; kk < 2; ++kk)
          Aw[m][kk] = *(const bf16x8*)&wl[(co0 + m * 16 + l15) * 72 + kk * 32 + q * 8];
      f32x4 acc[2][2];
#pragma unroll
      for (int m = 0; m < 2; ++m)
#pragma unroll
        for (int n2 = 0; n2 < 2; ++n2) acc[m][n2] = (f32x4){0.f, 0.f, 0.f, 0.f};
#pragma unroll
      for (int kk = 0; kk < 2; ++kk)
#pragma unroll
        for (int n2 = 0; n2 < 2; ++n2)
#pragma unroll
          for (int m = 0; m < 2; ++m)
            acc[m][n2] = MFMA16(Aw[m][kk], Bx[n2][kk], acc[m][n2]);

      float s1 = 0.f, s2 = 0.f;
#pragma unroll
      for (int m = 0; m < 2; ++m)
#pragma unroll
        for (int n2 = 0; n2 < 2; ++n2)
#pragma unroll
          for (int rg = 0; rg < 4; ++rg) {
            float y = acc[m][n2][rg] + biasl[co0 + m * 16 + 4 * q + rg];
            acc[m][n2][rg] = y;
            s1 += y; s2 += y * y;
          }
#pragma unroll
      for (int mask = 32; mask >= 1; mask >>= 1) {
        s1 += __shfl_xor(s1, mask, 64);
        s2 += __shfl_xor(s2, mask, 64);
      }

      __syncthreads();   // previous ngs's yl global-store reads done
      if (lane == 0) { redbuf[wid * 2] = s1; redbuf[wid * 2 + 1] = s2; }
      if (br == 0) {   // yl: [32 c][136 p]
#pragma unroll
        for (int m = 0; m < 2; ++m)
#pragma unroll
          for (int n2 = 0; n2 < 2; ++n2)
#pragma unroll
            for (int rg = 0; rg < 4; ++rg)
              yl[(m * 16 + 4 * q + rg) * 136 + (wid * 2 + n2) * 16 + l15] = f2bf(acc[m][n2][rg]);
      } else {         // yl: [128 p][40 c]
#pragma unroll
        for (int m = 0; m < 2; ++m)
#pragma unroll
          for (int n2 = 0; n2 < 2; ++n2)
#pragma unroll
            for (int rg = 0; rg < 4; ++rg)
              yl[((wid * 2 + n2) * 16 + l15) * 40 + m * 16 + 4 * q + rg] = f2bf(acc[m][n2][rg]);
      }
      __syncthreads();

      if (br == 0) {
#pragma unroll
        for (int r = 0; r < 2; ++r) {
          int chunk = tid + 256 * r;
          int row = chunk >> 4, ch = chunk & 15;
          *(uint4*)&dst[((size_t)(b * 1024 + g * 128 + co0 + row)) * 2048 + pc * 128 + ch * 8] =
              *(const uint4*)&yl[row * 136 + ch * 8];
        }
      } else {
#pragma unroll
        for (int r = 0; r < 2; ++r) {
          int chunk = tid + 256 * r;
          int row = chunk >> 2, ch = chunk & 3;
          *(uint4*)&dst[((size_t)(b * 8 + g) * 2048 + pc * 128 + row) * 128 + co0 + ch * 8] =
              *(const uint4*)&yl[row * 40 + ch * 8];
        }
      }
      if (tid == 0) {
        float S1 = redbuf[0] + redbuf[2] + redbuf[4] + redbuf[6];
        float S2 = redbuf[1] + redbuf[3] + redbuf[5] + redbuf[7];
        int sidx = (br * 8 + b) * 32 + g * 4 + ngs;
        atomicAdd(&stats[2 * sidx], S1);
        atomicAdd(&stats[2 * sidx + 1], S2);
      }
    }
  }
}

// ---------------------------------------------------------------------------
// Kernel 2: in-place GroupNorm affine + LeakyReLU over the 3 contiguous bufs.
// ---------------------------------------------------------------------------
__global__ __launch_bounds__(256) void gn_apply(
    ushort_t* __restrict__ buf, const float* __restrict__ stats,
    const float* __restrict__ gw1, const float* __restrict__ gb1,
    const float* __restrict__ gw2, const float* __restrict__ gb2,
    const float* __restrict__ gw3, const float* __restrict__ gb3) {
  const unsigned NQ = 16777216u;
  unsigned gid = blockIdx.x * 256 + threadIdx.x;
  unsigned e = gid * 8;
  int br; unsigned local;
  if (e < NQ)            { br = 0; local = e; }
  else if (e < 2u * NQ)  { br = 1; local = e - NQ; }
  else                   { br = 2; local = e - 2u * NQ; }
  int b, c0;
  if (br == 0) { b = local >> 21; c0 = (local >> 11) & 1023; }
  else {
    int cih = local & 127; int h = (local >> 18) & 7;
    b = local >> 21; c0 = h * 128 + cih;
  }
  int ng = c0 >> 5;
  const float* gw = (br == 0) ? gw1 : ((br == 1) ? gw2 : gw3);
  const float* gb = (br == 0) ? gb1 : ((br == 1) ? gb2 : gb3);
  int sidx = (br * 8 + b) * 32 + ng;
  float mean = stats[2 * sidx] * (1.f / 65536.f);
  float var  = stats[2 * sidx + 1] * (1.f / 65536.f) - mean * mean;
  float rstd = rsqrtf(var + 1e-5f);
  uint4 d = *(uint4*)&buf[(size_t)e];
  ushort_t* pu = (ushort_t*)&d;
#pragma unroll
  for (int i = 0; i < 8; ++i) {
    int ci = (br == 0) ? c0 : (c0 + i);
    float a = rstd * gw[ci];
    float b2 = gb[ci] - mean * a;
    float yn = fmaf(bf2f(pu[i]), a, b2);
    yn = (yn >= 0.f) ? yn : 0.1f * yn;
    pu[i] = f2bf(yn);
  }
  *(uint4*)&buf[(size_t)e] = d;
}

// ---------------------------------------------------------------------------
// Kernel 3: flash attention, 32x32x16 MFMA, LDS-staged, S^T formulation.
// flashQ=K-branch [B,H,P,128] (i), flashK=V-branch [B,H,P,128] (j),
// flashV=Q-branch [B,C,P] (c rows, p=j cols).
// Block: i-tile 256 (4 waves x 64 i = 2 n-tiles), j-tile 32, grid (8,64).
// S^T = fK.fQ^T: A = fK tile from LDS (staged coalesced), B = fQ resident
//   regs -> each A read feeds 2 MFMAs. C layout puts i on lane&31: softmax
//   m/l one scalar per (lane,nt), reduce = in-lane + 1 shfl_xor(32).
// P^T -> wave-private LDS rows (no barrier). O^T = V.P^T: A = V tile from
//   LDS, B = P^T. O has i on lanes -> broadcast rescale, coalesced stores.
// 2 barriers/jt. LDS 39.4 KB -> 4 blocks/CU. Frag layouts verified by R4.
// ---------------------------------------------------------------------------
__global__ void attn(
    const ushort_t* __restrict__ Qb, const ushort_t* __restrict__ Kb,
    const ushort_t* __restrict__ Vb, float* __restrict__ out) {
  __shared__ __align__(16) ushort_t fKs[32 * 136];   // [j][d]   8704 B
  __shared__ __align__(16) ushort_t Vs[128 * 40];    // [c][j]  10240 B
  __shared__ __align__(16) ushort_t Ps[256 * 40];    // [i][j]  20480 B

  int it = blockIdx.x, bh = blockIdx.y;
  int b = bh >> 3, h = bh & 7;
  int tid = threadIdx.x, lane = tid & 63, wid = tid >> 6;
  int l31 = lane & 31, q2 = lane >> 5;
  const float scale = 0.08838834764831845f;   // 1/sqrt(128)

  // resident fQ B-frags: B[k=d][n=i], n-col = l31 -> row i (one-time load)
  bf16x8 Bq[2][8];
#pragma unroll
  for (int nt = 0; nt < 2; ++nt) {
    const ushort_t* fQp =
        Kb + ((size_t)bh * 2048 + it * 256 + wid * 64 + nt * 32 + l31) * 128 + q2 * 8;
#pragma unroll
    for (int dc = 0; dc < 8; ++dc) Bq[nt][dc] = *(const bf16x8*)&fQp[dc * 16];
  }

  float m_i[2], l_i[2];
  m_i[0] = m_i[1] = -1e30f;
  l_i[0] = l_i[1] = 0.f;
  f32x16 O[4][2];
#pragma unroll
  for (int mt = 0; mt < 4; ++mt)
#pragma unroll
    for (int nt = 0; nt < 2; ++nt) O[mt][nt] = (f32x16)(0.f);

  const ushort_t* fKg = Vb + (size_t)bh * 2048 * 128;
  const ushort_t* fVg = Qb + ((size_t)(b * 1024 + h * 128)) * 2048;

  for (int jt = 0; jt < 64; ++jt) {
    // stage fK tile [32 j][128 d] and V tile [128 c][32 j], coalesced
#pragma unroll
    for (int r = 0; r < 2; ++r) {
      int n = tid + 256 * r;
      { int row = n >> 4, c = n & 15;
        *(uint4*)&fKs[row * 136 + c * 8] =
            *(const uint4*)&fKg[(size_t)(jt * 32 + row) * 128 + c * 8]; }
      { int crow = n >> 2, jc8 = n & 3;
        *(uint4*)&Vs[crow * 40 + jc8 * 8] =
            *(const uint4*)&fVg[(size_t)crow * 2048 + jt * 32 + jc8 * 8]; }
    }
    __syncthreads();   // #1 tiles visible

    // S^T = fK . fQ^T : 8 A-reads, 16 MFMAs
    f32x16 ST[2];
    ST[0] = (f32x16)(0.f);
    ST[1] = (f32x16)(0.f);
#pragma unroll
    for (int dc = 0; dc < 8; ++dc) {
      bf16x8 Ak = *(const bf16x8*)&fKs[l31 * 136 + dc * 16 + q2 * 8];
      ST[0] = MFMA32(Ak, Bq[0][dc], ST[0]);
      ST[1] = MFMA32(Ak, Bq[1][dc], ST[1]);
    }

    // online softmax over j; lane covers i = nt*32+l31 (j split across q2)
    float al[2];
#pragma unroll
    for (int nt = 0; nt < 2; ++nt) {
      float vmax = ST[nt][0];
#pragma unroll
      for (int rg = 1; rg < 16; ++rg) vmax = fmaxf(vmax, ST[nt][rg]);
      vmax *= scale;
      vmax = fmaxf(vmax, __shfl_xor(vmax, 32, 64));
      float mn = fmaxf(m_i[nt], vmax);
      al[nt] = __expf(m_i[nt] - mn);
      m_i[nt] = mn;
      float rs = 0.f;
      int prow = (wid * 64 + nt * 32 + l31) * 40;
#pragma unroll
      for (int r = 0; r < 4; ++r) {
        float p0 = __expf(fmaf(ST[nt][4 * r + 0], scale, -mn));
        float p1 = __expf(fmaf(ST[nt][4 * r + 1], scale, -mn));
        float p2 = __expf(fmaf(ST[nt][4 * r + 2], scale, -mn));
        float p3 = __expf(fmaf(ST[nt][4 * r + 3], scale, -mn));
        rs += (p0 + p1) + (p2 + p3);
        ushort4 pk;
        pk.x = f2bf(p0); pk.y = f2bf(p1); pk.z = f2bf(p2); pk.w = f2bf(p3);
        // j = 8r + 4q2 + {0..3}
        *(ushort4*)&Ps[prow + r * 8 + q2 * 4] = pk;
      }
      rs += __shfl_xor(rs, 32, 64);
      l_i[nt] = l_i[nt] * al[nt] + rs;
    }

    // O rescale (i on lanes -> broadcast)
#pragma unroll
    for (int mt = 0; mt < 4; ++mt)
#pragma unroll
      for (int nt = 0; nt < 2; ++nt)
#pragma unroll
        for (int rg = 0; rg < 16; ++rg) O[mt][nt][rg] *= al[nt];

    // O^T += V . P^T : 8 V-reads + 4 P-reads, 16 MFMAs (P wave-private)
#pragma unroll
    for (int jc = 0; jc < 2; ++jc) {
      bf16x8 Bp[2];
#pragma unroll
      for (int nt = 0; nt < 2; ++nt)
        Bp[nt] = *(const bf16x8*)&Ps[(wid * 64 + nt * 32 + l31) * 40 + jc * 16 + q2 * 8];
#pragma unroll
      for (int mt = 0; mt < 4; ++mt) {
        bf16x8 Av = *(const bf16x8*)&Vs[(mt * 32 + l31) * 40 + jc * 16 + q2 * 8];
        O[mt][0] = MFMA32(Av, Bp[0], O[mt][0]);
        O[mt][1] = MFMA32(Av, Bp[1], O[mt][1]);
      }
    }
    __syncthreads();   // #2 before next staging overwrites fKs/Vs
  }

  // epilogue: i on lanes -> direct coalesced stores
  float linv[2];
  linv[0] = 1.f / l_i[0];
  linv[1] = 1.f / l_i[1];
#pragma unroll
  for (int mt = 0; mt < 4; ++mt)
#pragma unroll
    for (int nt = 0; nt < 2; ++nt) {
      float* obase = out + ((size_t)(b * 1024 + h * 128 + mt * 32)) * 2048 +
                     it * 256 + wid * 64 + nt * 32 + l31;
#pragma unroll
      for (int rg = 0; rg < 16; ++rg) {
        int c = (rg & 3) + 8 * (rg >> 2) + 4 * q2;
        obase[(size_t)c * 2048] = O[mt][nt][rg] * linv[nt];
      }
    }
}

// ---------------------------------------------------------------------------
extern "C" void kernel_launch(void* const* d_in, const int* in_sizes, int n_in,
                              void* d_out, int out_size, void* d_ws, size_t ws_size,
                              hipStream_t stream) {
  const float* x   = (const float*)d_in[0];
  const float* wq  = (const float*)d_in[1];
  const float* bq  = (const float*)d_in[2];
  const float* gw1 = (const float*)d_in[3];
  const float* gb1 = (const float*)d_in[4];
  const float* wk  = (const float*)d_in[5];
  const float* bk  = (const float*)d_in[6];
  const float* gw2 = (const float*)d_in[7];
  const float* gb2 = (const float*)d_in[8];
  const float* wv  = (const float*)d_in[9];
  const float* bv  = (const float*)d_in[10];
  const float* gw3 = (const float*)d_in[11];
  const float* gb3 = (const float*)d_in[12];
  float* out = (float*)d_out;
  char* ws = (char*)d_ws;

  ushort_t* Qb = (ushort_t*)(ws);               // 33,554,432 B  [B,C,P] bf16
  ushort_t* Kb = (ushort_t*)(ws + 33554432);    // 33,554,432 B  [B,H,P,128] bf16
  ushort_t* Vb = (ushort_t*)(ws + 67108864);    // 33,554,432 B  [B,H,P,128] bf16
  float* stats = (float*)(ws + 100663296);      // 768 groups x {s1,s2}

  hipMemsetAsync(stats, 0, 1536 * sizeof(float), stream);
  conv_gn<<<dim3(16, 64), 256, 0, stream>>>(x, wq, wk, wv, bq, bk, bv,
                                            Qb, Kb, Vb, stats);
  gn_apply<<<24576, 256, 0, stream>>>(Qb, stats, gw1, gb1, gw2, gb2, gw3, gb3);
  attn<<<dim3(8, 64), 256, 0, stream>>>(Qb, Kb, Vb, out);
}

// Round 6
// 505.170 us; speedup vs baseline: 5.0433x; 5.0433x over previous
//
#include <hip/hip_runtime.h>

typedef unsigned short ushort_t;
typedef float  f32x4   __attribute__((ext_vector_type(4)));
typedef float  f32x16  __attribute__((ext_vector_type(16)));
typedef __bf16 bf16x8  __attribute__((ext_vector_type(8)));

#define MFMA16(a,b,c) __builtin_amdgcn_mfma_f32_16x16x32_bf16((a),(b),(c),0,0,0)
#define MFMA32(a,b,c) __builtin_amdgcn_mfma_f32_32x32x16_bf16((a),(b),(c),0,0,0)

__device__ __forceinline__ ushort_t f2bf(float f) {
  union { float f; unsigned u; } v; v.f = f;
  unsigned u = v.u;
  unsigned r = u + 0x7FFFu + ((u >> 16) & 1u);   // round-to-nearest-even
  return (ushort_t)(r >> 16);
}
__device__ __forceinline__ float bf2f(ushort_t s) {
  union { unsigned u; float f; } v; v.u = ((unsigned)s) << 16;
  return v.f;
}

// ---------------------------------------------------------------------------
// Kernel 1: fused grouped conv (MFMA) + bias; x staged once per block (f32 ->
// bf16 transpose in LDS), loops 3 branches x 4 ngsub. Writes unnormalized y
// in final layouts; accumulates GroupNorm partial sums via atomics.
// grid (pc=16, g*b=64), 256 thr.
// Q branch -> [B][C][P]; K/V branches -> [B][H][P][128].
// ---------------------------------------------------------------------------
__global__ __launch_bounds__(256) void conv_gn(
    const float* __restrict__ x,
    const float* __restrict__ wq, const float* __restrict__ wk, const float* __restrict__ wv,
    const float* __restrict__ bq, const float* __restrict__ bk, const float* __restrict__ bv,
    ushort_t* __restrict__ Qb, ushort_t* __restrict__ Kb, ushort_t* __restrict__ Vb,
    float* __restrict__ stats) {
  int pc = blockIdx.x;
  int gz = blockIdx.y;
  int b = gz & 7, g = gz >> 3;
  int tid = threadIdx.x, lane = tid & 63, wid = tid >> 6;
  int l15 = lane & 15, q = lane >> 4;

  __shared__ __align__(16) ushort_t xl[128 * 72];   // [p][f]
  __shared__ __align__(16) ushort_t wl[128 * 72];   // [co][f], one branch
  __shared__ __align__(16) ushort_t yl[128 * 40];   // staging (br=0 uses [32][136])
  __shared__ float biasl[128];
  __shared__ float redbuf[8];

  // stage x tile [64 f][128 p] f32 -> xl[p][f] bf16
  const float* xsrc = x + ((size_t)(b * 512 + g * 64)) * 2048 + pc * 128;
#pragma unroll
  for (int r = 0; r < 8; ++r) {
    int chunk = tid + 256 * r;
    int c = chunk >> 5, p4 = chunk & 31;
    float4 v = *(const float4*)&xsrc[(size_t)c * 2048 + p4 * 4];
    xl[(p4 * 4 + 0) * 72 + c] = f2bf(v.x);
    xl[(p4 * 4 + 1) * 72 + c] = f2bf(v.y);
    xl[(p4 * 4 + 2) * 72 + c] = f2bf(v.z);
    xl[(p4 * 4 + 3) * 72 + c] = f2bf(v.w);
  }
  __syncthreads();

  // resident B-frags (wave's 32 p-cols)
  bf16x8 Bx[2][2];
#pragma unroll
  for (int n2 = 0; n2 < 2; ++n2)
#pragma unroll
    for (int kk = 0; kk < 2; ++kk)
      Bx[n2][kk] = *(const bf16x8*)&xl[((wid * 2 + n2) * 16 + l15) * 72 + kk * 32 + q * 8];

  for (int br = 0; br < 3; ++br) {
    const float* w    = (br == 0) ? wq : ((br == 1) ? wk : wv);
    const float* bias = (br == 0) ? bq : ((br == 1) ? bk : bv);
    ushort_t* dst     = (br == 0) ? Qb : ((br == 1) ? Kb : Vb);
    __syncthreads();   // previous branch's wl/yl consumers done
    const float* wsrc = w + (size_t)g * 128 * 64;
#pragma unroll
    for (int r = 0; r < 8; ++r) {
      int idx = (tid + 256 * r) << 2;
      float4 v = *(const float4*)&wsrc[idx];
      int row = idx >> 6, f = idx & 63;
      wl[row * 72 + f + 0] = f2bf(v.x);
      wl[row * 72 + f + 1] = f2bf(v.y);
      wl[row * 72 + f + 2] = f2bf(v.z);
      wl[row * 72 + f + 3] = f2bf(v.w);
    }
    if (tid < 128) biasl[tid] = bias[g * 128 + tid];
    __syncthreads();

    for (int ngs = 0; ngs < 4; ++ngs) {
      int co0 = ngs * 32;
      bf16x8 Aw[2][2];
#pragma unroll
      for (int m = 0; m < 2; ++m)
#pragma unroll
        for (int kk = 0; kk < 2; ++kk)
          Aw[m][kk] = *(const bf16x8*)&wl[(co0 + m * 16 + l15) * 72 + kk * 32 + q * 8];
      f32x4 acc[2][2];
#pragma unroll
      for (int m = 0; m < 2; ++m)
#pragma unroll
        for (int n2 = 0; n2 < 2; ++n2) acc[m][n2] = (f32x4){0.f, 0.f, 0.f, 0.f};
#pragma unroll
      for (int kk = 0; kk < 2; ++kk)
#pragma unroll
        for (int n2 = 0; n2 < 2; ++n2)
#pragma unroll
          for (int m = 0; m < 2; ++m)
            acc[m][n2] = MFMA16(Aw[m][kk], Bx[n2][kk], acc[m][n2]);

      float s1 = 0.f, s2 = 0.f;
#pragma unroll
      for (int m = 0; m < 2; ++m)
#pragma unroll
        for (int n2 = 0; n2 < 2; ++n2)
#pragma unroll
          for (int rg = 0; rg < 4; ++rg) {
            float y = acc[m][n2][rg] + biasl[co0 + m * 16 + 4 * q + rg];
            acc[m][n2][rg] = y;
            s1 += y; s2 += y * y;
          }
#pragma unroll
      for (int mask = 32; mask >= 1; mask >>= 1) {
        s1 += __shfl_xor(s1, mask, 64);
        s2 += __shfl_xor(s2, mask, 64);
      }

      __syncthreads();   // previous ngs's yl global-store reads done
      if (lane == 0) { redbuf[wid * 2] = s1; redbuf[wid * 2 + 1] = s2; }
      if (br == 0) {   // yl: [32 c][136 p]
#pragma unroll
        for (int m = 0; m < 2; ++m)
#pragma unroll
          for (int n2 = 0; n2 < 2; ++n2)
#pragma unroll
            for (int rg = 0; rg < 4; ++rg)
              yl[(m * 16 + 4 * q + rg) * 136 + (wid * 2 + n2) * 16 + l15] = f2bf(acc[m][n2][rg]);
      } else {         // yl: [128 p][40 c]
#pragma unroll
        for (int m = 0; m < 2; ++m)
#pragma unroll
          for (int n2 = 0; n2 < 2; ++n2)
#pragma unroll
            for (int rg = 0; rg < 4; ++rg)
              yl[((wid * 2 + n2) * 16 + l15) * 40 + m * 16 + 4 * q + rg] = f2bf(acc[m][n2][rg]);
      }
      __syncthreads();

      if (br == 0) {
#pragma unroll
        for (int r = 0; r < 2; ++r) {
          int chunk = tid + 256 * r;
          int row = chunk >> 4, ch = chunk & 15;
          *(uint4*)&dst[((size_t)(b * 1024 + g * 128 + co0 + row)) * 2048 + pc * 128 + ch * 8] =
              *(const uint4*)&yl[row * 136 + ch * 8];
        }
      } else {
#pragma unroll
        for (int r = 0; r < 2; ++r) {
          int chunk = tid + 256 * r;
          int row = chunk >> 2, ch = chunk & 3;
          *(uint4*)&dst[((size_t)(b * 8 + g) * 2048 + pc * 128 + row) * 128 + co0 + ch * 8] =
              *(const uint4*)&yl[row * 40 + ch * 8];
        }
      }
      if (tid == 0) {
        float S1 = redbuf[0] + redbuf[2] + redbuf[4] + redbuf[6];
        float S2 = redbuf[1] + redbuf[3] + redbuf[5] + redbuf[7];
        int sidx = (br * 8 + b) * 32 + g * 4 + ngs;
        atomicAdd(&stats[2 * sidx], S1);
        atomicAdd(&stats[2 * sidx + 1], S2);
      }
    }
  }
}

// ---------------------------------------------------------------------------
// Kernel 2: in-place GroupNorm affine + LeakyReLU over the 3 contiguous bufs.
// ---------------------------------------------------------------------------
__global__ __launch_bounds__(256) void gn_apply(
    ushort_t* __restrict__ buf, const float* __restrict__ stats,
    const float* __restrict__ gw1, const float* __restrict__ gb1,
    const float* __restrict__ gw2, const float* __restrict__ gb2,
    const float* __restrict__ gw3, const float* __restrict__ gb3) {
  const unsigned NQ = 16777216u;
  unsigned gid = blockIdx.x * 256 + threadIdx.x;
  unsigned e = gid * 8;
  int br; unsigned local;
  if (e < NQ)            { br = 0; local = e; }
  else if (e < 2u * NQ)  { br = 1; local = e - NQ; }
  else                   { br = 2; local = e - 2u * NQ; }
  int b, c0;
  if (br == 0) { b = local >> 21; c0 = (local >> 11) & 1023; }
  else {
    int cih = local & 127; int h = (local >> 18) & 7;
    b = local >> 21; c0 = h * 128 + cih;
  }
  int ng = c0 >> 5;
  const float* gw = (br == 0) ? gw1 : ((br == 1) ? gw2 : gw3);
  const float* gb = (br == 0) ? gb1 : ((br == 1) ? gb2 : gb3);
  int sidx = (br * 8 + b) * 32 + ng;
  float mean = stats[2 * sidx] * (1.f / 65536.f);
  float var  = stats[2 * sidx + 1] * (1.f / 65536.f) - mean * mean;
  float rstd = rsqrtf(var + 1e-5f);
  uint4 d = *(uint4*)&buf[(size_t)e];
  ushort_t* pu = (ushort_t*)&d;
#pragma unroll
  for (int i = 0; i < 8; ++i) {
    int ci = (br == 0) ? c0 : (c0 + i);
    float a = rstd * gw[ci];
    float b2 = gb[ci] - mean * a;
    float yn = fmaf(bf2f(pu[i]), a, b2);
    yn = (yn >= 0.f) ? yn : 0.1f * yn;
    pu[i] = f2bf(yn);
  }
  *(uint4*)&buf[(size_t)e] = d;
}

// ---------------------------------------------------------------------------
// Kernel 3: flash attention, 32x32x16 MFMA, LDS-staged, S^T formulation.
// flashQ=K-branch [B,H,P,128] (i), flashK=V-branch [B,H,P,128] (j),
// flashV=Q-branch [B,C,P] (c rows, p=j cols).
// Block: i-tile 256 (4 waves x 64 i = 2 n-tiles), j-tile 32, grid (8,64).
// S^T = fK.fQ^T: A = fK tile from LDS (staged coalesced), B = fQ resident
//   regs -> each A read feeds 2 MFMAs. C layout puts i on lane&31: softmax
//   m/l one scalar per (lane,nt), reduce = in-lane + 1 shfl_xor(32).
// P^T -> wave-private LDS rows (no barrier). O^T = V.P^T: A = V tile from
//   LDS, B = P^T. O has i on lanes -> broadcast rescale, coalesced stores.
// 2 barriers/jt. LDS 39.4 KB. __launch_bounds__(256,2): 256 unified
// VGPR+AGPR/wave — fits Bq(64)+O(128 acc)+ST(32)+temps without spill.
// (R5 lesson: omitting launch_bounds -> 64-VGPR cap -> 6.6 GB scratch spill.)
// ---------------------------------------------------------------------------
__global__ __launch_bounds__(256, 2) void attn(
    const ushort_t* __restrict__ Qb, const ushort_t* __restrict__ Kb,
    const ushort_t* __restrict__ Vb, float* __restrict__ out) {
  __shared__ __align__(16) ushort_t fKs[32 * 136];   // [j][d]   8704 B
  __shared__ __align__(16) ushort_t Vs[128 * 40];    // [c][j]  10240 B
  __shared__ __align__(16) ushort_t Ps[256 * 40];    // [i][j]  20480 B

  int it = blockIdx.x, bh = blockIdx.y;
  int b = bh >> 3, h = bh & 7;
  int tid = threadIdx.x, lane = tid & 63, wid = tid >> 6;
  int l31 = lane & 31, q2 = lane >> 5;
  const float scale = 0.08838834764831845f;   // 1/sqrt(128)

  // resident fQ B-frags: B[k=d][n=i], n-col = l31 -> row i (one-time load)
  bf16x8 Bq[2][8];
#pragma unroll
  for (int nt = 0; nt < 2; ++nt) {
    const ushort_t* fQp =
        Kb + ((size_t)bh * 2048 + it * 256 + wid * 64 + nt * 32 + l31) * 128 + q2 * 8;
#pragma unroll
    for (int dc = 0; dc < 8; ++dc) Bq[nt][dc] = *(const bf16x8*)&fQp[dc * 16];
  }

  float m_i[2], l_i[2];
  m_i[0] = m_i[1] = -1e30f;
  l_i[0] = l_i[1] = 0.f;
  f32x16 O[4][2];
#pragma unroll
  for (int mt = 0; mt < 4; ++mt)
#pragma unroll
    for (int nt = 0; nt < 2; ++nt) O[mt][nt] = (f32x16)(0.f);

  const ushort_t* fKg = Vb + (size_t)bh * 2048 * 128;
  const ushort_t* fVg = Qb + ((size_t)(b * 1024 + h * 128)) * 2048;

  for (int jt = 0; jt < 64; ++jt) {
    // stage fK tile [32 j][128 d] and V tile [128 c][32 j], coalesced
#pragma unroll
    for (int r = 0; r < 2; ++r) {
      int n = tid + 256 * r;
      { int row = n >> 4, c = n & 15;
        *(uint4*)&fKs[row * 136 + c * 8] =
            *(const uint4*)&fKg[(size_t)(jt * 32 + row) * 128 + c * 8]; }
      { int crow = n >> 2, jc8 = n & 3;
        *(uint4*)&Vs[crow * 40 + jc8 * 8] =
            *(const uint4*)&fVg[(size_t)crow * 2048 + jt * 32 + jc8 * 8]; }
    }
    __syncthreads();   // #1 tiles visible

    // S^T = fK . fQ^T : 8 A-reads, 16 MFMAs
    f32x16 ST[2];
    ST[0] = (f32x16)(0.f);
    ST[1] = (f32x16)(0.f);
#pragma unroll
    for (int dc = 0; dc < 8; ++dc) {
      bf16x8 Ak = *(const bf16x8*)&fKs[l31 * 136 + dc * 16 + q2 * 8];
      ST[0] = MFMA32(Ak, Bq[0][dc], ST[0]);
      ST[1] = MFMA32(Ak, Bq[1][dc], ST[1]);
    }

    // online softmax over j; lane covers i = nt*32+l31 (j split across q2)
    float al[2];
#pragma unroll
    for (int nt = 0; nt < 2; ++nt) {
      float vmax = ST[nt][0];
#pragma unroll
      for (int rg = 1; rg < 16; ++rg) vmax = fmaxf(vmax, ST[nt][rg]);
      vmax *= scale;
      vmax = fmaxf(vmax, __shfl_xor(vmax, 32, 64));
      float mn = fmaxf(m_i[nt], vmax);
      al[nt] = __expf(m_i[nt] - mn);
      m_i[nt] = mn;
      float rs = 0.f;
      int prow = (wid * 64 + nt * 32 + l31) * 40;
#pragma unroll
      for (int r = 0; r < 4; ++r) {
        float p0 = __expf(fmaf(ST[nt][4 * r + 0], scale, -mn));
        float p1 = __expf(fmaf(ST[nt][4 * r + 1], scale, -mn));
        float p2 = __expf(fmaf(ST[nt][4 * r + 2], scale, -mn));
        float p3 = __expf(fmaf(ST[nt][4 * r + 3], scale, -mn));
        rs += (p0 + p1) + (p2 + p3);
        ushort4 pk;
        pk.x = f2bf(p0); pk.y = f2bf(p1); pk.z = f2bf(p2); pk.w = f2bf(p3);
        // j = 8r + 4q2 + {0..3}
        *(ushort4*)&Ps[prow + r * 8 + q2 * 4] = pk;
      }
      rs += __shfl_xor(rs, 32, 64);
      l_i[nt] = l_i[nt] * al[nt] + rs;
    }

    // O rescale (i on lanes -> broadcast)
#pragma unroll
    for (int mt = 0; mt < 4; ++mt)
#pragma unroll
      for (int nt = 0; nt < 2; ++nt)
#pragma unroll
        for (int rg = 0; rg < 16; ++rg) O[mt][nt][rg] *= al[nt];

    // O^T += V . P^T : 8 V-reads + 4 P-reads, 16 MFMAs (P wave-private)
#pragma unroll
    for (int jc = 0; jc < 2; ++jc) {
      bf16x8 Bp[2];
#pragma unroll
      for (int nt = 0; nt < 2; ++nt)
        Bp[nt] = *(const bf16x8*)&Ps[(wid * 64 + nt * 32 + l31) * 40 + jc * 16 + q2 * 8];
#pragma unroll
      for (int mt = 0; mt < 4; ++mt) {
        bf16x8 Av = *(const bf16x8*)&Vs[(mt * 32 + l31) * 40 + jc * 16 + q2 * 8];
        O[mt][0] = MFMA32(Av, Bp[0], O[mt][0]);
        O[mt][1] = MFMA32(Av, Bp[1], O[mt][1]);
      }
    }
    __syncthreads();   // #2 before next staging overwrites fKs/Vs
  }

  // epilogue: i on lanes -> direct coalesced stores
  float linv[2];
  linv[0] = 1.f / l_i[0];
  linv[1] = 1.f / l_i[1];
#pragma unroll
  for (int mt = 0; mt < 4; ++mt)
#pragma unroll
    for (int nt = 0; nt < 2; ++nt) {
      float* obase = out + ((size_t)(b * 1024 + h * 128 + mt * 32)) * 2048 +
                     it * 256 + wid * 64 + nt * 32 + l31;
#pragma unroll
      for (int rg = 0; rg < 16; ++rg) {
        int c = (rg & 3) + 8 * (rg >> 2) + 4 * q2;
        obase[(size_t)c * 2048] = O[mt][nt][rg] * linv[nt];
      }
    }
}

// ---------------------------------------------------------------------------
extern "C" void kernel_launch(void* const* d_in, const int* in_sizes, int n_in,
                              void* d_out, int out_size, void* d_ws, size_t ws_size,
                              hipStream_t stream) {
  const float* x   = (const float*)d_in[0];
  const float* wq  = (const float*)d_in[1];
  const float* bq  = (const float*)d_in[2];
  const float* gw1 = (const float*)d_in[3];
  const float* gb1 = (const float*)d_in[4];
  const float* wk  = (const float*)d_in[5];
  const float* bk  = (const float*)d_in[6];
  const float* gw2 = (const float*)d_in[7];
  const float* gb2 = (const float*)d_in[8];
  const float* wv  = (const float*)d_in[9];
  const float* bv  = (const float*)d_in[10];
  const float* gw3 = (const float*)d_in[11];
  const float* gb3 = (const float*)d_in[12];
  float* out = (float*)d_out;
  char* ws = (char*)d_ws;

  ushort_t* Qb = (ushort_t*)(ws);               // 33,554,432 B  [B,C,P] bf16
  ushort_t* Kb = (ushort_t*)(ws + 33554432);    // 33,554,432 B  [B,H,P,128] bf16
  ushort_t* Vb = (ushort_t*)(ws + 67108864);    // 33,554,432 B  [B,H,P,128] bf16
  float* stats = (float*)(ws + 100663296);      // 768 groups x {s1,s2}

  hipMemsetAsync(stats, 0, 1536 * sizeof(float), stream);
  conv_gn<<<dim3(16, 64), 256, 0, stream>>>(x, wq, wk, wv, bq, bk, bv,
                                            Qb, Kb, Vb, stats);
  gn_apply<<<24576, 256, 0, stream>>>(Qb, stats, gw1, gb1, gw2, gb2, gw3, gb3);
  attn<<<dim3(8, 64), 256, 0, stream>>>(Qb, Kb, Vb, out);
}